// Round 1
// baseline (285.319 us; speedup 1.0000x reference)
//
#include <hip/hip_runtime.h>
#include <math.h>

#define PP 8192
#define DD 4096
#define BBATCH 4
#define NTOT (BBATCH * PP)   // 32768
#define K_LOW 29490          // floor(0.9 * (NTOT-1))

// ---------------- Kernel 1: a = x @ W^T + b  -> [B, P] ----------------
// One wave (64 lanes) per output row p; 4 batch accumulators per lane.
// f32 fma within each float4 chunk, f64 accumulation across chunks
// (keeps result within ~3e-7 of the fp64 reference).
__global__ __launch_bounds__(256) void gemm_kernel(const float* __restrict__ x,
                                                   const float* __restrict__ W,
                                                   const float* __restrict__ bias,
                                                   float* __restrict__ a) {
  const int wave = threadIdx.x >> 6;
  const int lane = threadIdx.x & 63;
  const int p = (blockIdx.x << 2) + wave;
  if (p >= PP) return;
  const float4* __restrict__ Wrow = (const float4*)(W + (size_t)p * DD);
  const float4* __restrict__ x4 = (const float4*)x;
  double acc0 = 0.0, acc1 = 0.0, acc2 = 0.0, acc3 = 0.0;
  #pragma unroll 4
  for (int i = lane; i < DD / 4; i += 64) {
    float4 w  = Wrow[i];
    float4 v0 = x4[i];
    float4 v1 = x4[1024 + i];
    float4 v2 = x4[2048 + i];
    float4 v3 = x4[3072 + i];
    acc0 += (double)fmaf(w.x, v0.x, fmaf(w.y, v0.y, fmaf(w.z, v0.z, w.w * v0.w)));
    acc1 += (double)fmaf(w.x, v1.x, fmaf(w.y, v1.y, fmaf(w.z, v1.z, w.w * v1.w)));
    acc2 += (double)fmaf(w.x, v2.x, fmaf(w.y, v2.y, fmaf(w.z, v2.z, w.w * v2.w)));
    acc3 += (double)fmaf(w.x, v3.x, fmaf(w.y, v3.y, fmaf(w.z, v3.z, w.w * v3.w)));
  }
  #pragma unroll
  for (int off = 32; off > 0; off >>= 1) {
    acc0 += __shfl_down(acc0, off);
    acc1 += __shfl_down(acc1, off);
    acc2 += __shfl_down(acc2, off);
    acc3 += __shfl_down(acc3, off);
  }
  if (lane == 0) {
    float bp = bias[p];
    a[0 * PP + p] = (float)acc0 + bp;
    a[1 * PP + p] = (float)acc1 + bp;
    a[2 * PP + p] = (float)acc2 + bp;
    a[3 * PP + p] = (float)acc3 + bp;
  }
}

// ---------------- Kernel 2: exact 0.9-quantile of |a| via radix select ----------------
// Non-negative float bit patterns are monotone as uint32. Select ranks
// K_LOW and K_LOW+1 (ascending, 0-indexed), then linear interpolation.
__global__ __launch_bounds__(1024) void select_kernel(const float* __restrict__ a,
                                                      float* __restrict__ thr_out) {
  __shared__ unsigned hist[256];
  __shared__ unsigned s_prefix;
  __shared__ unsigned s_rank;
  unsigned results[2];
  for (int sel = 0; sel < 2; ++sel) {
    unsigned prefix = 0;
    unsigned rank = (unsigned)(K_LOW + sel);
    for (int shift = 24; shift >= 0; shift -= 8) {
      for (int i = threadIdx.x; i < 256; i += 1024) hist[i] = 0;
      __syncthreads();
      const unsigned hmask = (shift == 24) ? 0u : (0xFFFFFFFFu << (shift + 8));
      for (int i = threadIdx.x; i < NTOT; i += 1024) {
        unsigned u = __float_as_uint(fabsf(a[i]));
        if ((u & hmask) == prefix) atomicAdd(&hist[(u >> shift) & 255], 1u);
      }
      __syncthreads();
      if (threadIdx.x == 0) {
        unsigned cum = 0;
        for (int bkt = 0; bkt < 256; ++bkt) {
          unsigned c = hist[bkt];
          if (cum + c > rank) {
            s_rank = rank - cum;
            s_prefix = prefix | ((unsigned)bkt << shift);
            break;
          }
          cum += c;
        }
      }
      __syncthreads();
      prefix = s_prefix;
      rank = s_rank;
      __syncthreads();
    }
    results[sel] = prefix;
  }
  if (threadIdx.x == 0) {
    double vlo = (double)__uint_as_float(results[0]);
    double vhi = (double)__uint_as_float(results[1]);
    double idx = 0.9 * (double)(NTOT - 1);
    double g = idx - floor(idx);
    thr_out[0] = (float)(vlo + g * (vhi - vlo));
  }
}

// ---------------- Kernel 3: state init + zero rec ----------------
__global__ void state_init_kernel(const float* __restrict__ a,
                                  const float* __restrict__ thr,
                                  const float* __restrict__ sstate,
                                  float* __restrict__ state,
                                  float* __restrict__ rec) {
  int p = blockIdx.x * blockDim.x + threadIdx.x;
  if (p < PP) {
    float a0 = a[p];  // row 0 of [B, P]
    float t = thr[0];
    state[p] = (fabsf(a0) > t) ? a0 : 0.9f * sstate[p];
    rec[p] = 0.0f;
  }
}

// ---------------- Kernel 4: COO SpMV with LDS accumulation ----------------
// s_state: LDS copy of state (fast random gather); s_rec: per-block LDS
// accumulator (LDS atomics), flushed to partials (clean) or via global atomics.
template <bool USE_PART>
__global__ __launch_bounds__(1024) void spmv_kernel(const float* __restrict__ vals,
                                                    const int* __restrict__ rows,
                                                    const int* __restrict__ cols,
                                                    const float* __restrict__ state,
                                                    float* __restrict__ dst,
                                                    int nc) {
  __shared__ float s_state[PP];
  __shared__ float s_rec[PP];
  for (int i = threadIdx.x; i < PP; i += 1024) {
    s_state[i] = state[i];
    s_rec[i] = 0.0f;
  }
  __syncthreads();
  const int stride = gridDim.x * 1024;
  for (int i = blockIdx.x * 1024 + threadIdx.x; i < nc; i += stride) {
    float v = vals[i];
    int r = rows[i];
    int c = cols[i];
    atomicAdd(&s_rec[r], v * s_state[c]);
  }
  __syncthreads();
  if (USE_PART) {
    float* part = dst + (size_t)blockIdx.x * PP;
    for (int i = threadIdx.x; i < PP; i += 1024) part[i] = s_rec[i];
  } else {
    for (int i = threadIdx.x; i < PP; i += 1024) atomicAdd(&dst[i], s_rec[i]);
  }
}

// ---------------- Kernel 4b: reduce partials -> rec ----------------
__global__ void reduce_partials_kernel(const float* __restrict__ part,
                                       float* __restrict__ rec, int nb) {
  int p = blockIdx.x * blockDim.x + threadIdx.x;
  if (p < PP) {
    float s = 0.0f;
    for (int b = 0; b < nb; ++b) s += part[(size_t)b * PP + p];
    rec[p] = s;
  }
}

// ---------------- Kernel 5: GELU + scalars ----------------
__global__ __launch_bounds__(1024) void finalize_kernel(const float* __restrict__ a,
                                                        const float* __restrict__ thr,
                                                        const float* __restrict__ state,
                                                        const float* __restrict__ rec,
                                                        float* __restrict__ out) {
  __shared__ float wsum[16];
  __shared__ unsigned wcnt[16];
  const float t = thr[0];
  float lsum = 0.0f;
  unsigned lcnt = 0;
  for (int p = threadIdx.x; p < PP; p += 1024) {
    float v = state[p] + 0.1f * rec[p];
    float ns = 0.5f * v * (1.0f + erff(v * 0.70710678118654752440f));
    out[p] = ns;
    if (fabsf(a[p]) > t) { lsum += ns; lcnt++; }
  }
  #pragma unroll
  for (int off = 32; off > 0; off >>= 1) {
    lsum += __shfl_down(lsum, off);
    lcnt += __shfl_down(lcnt, off);
  }
  const int lane = threadIdx.x & 63;
  const int wid = threadIdx.x >> 6;
  if (lane == 0) { wsum[wid] = lsum; wcnt[wid] = lcnt; }
  __syncthreads();
  if (threadIdx.x == 0) {
    float s = 0.0f;
    unsigned c = 0;
    for (int w = 0; w < 16; ++w) { s += wsum[w]; c += wcnt[w]; }
    out[PP] = (float)c;
    out[PP + 1] = (c > 0) ? (s / (float)c) : 0.0f;
  }
}

extern "C" void kernel_launch(void* const* d_in, const int* in_sizes, int n_in,
                              void* d_out, int out_size, void* d_ws, size_t ws_size,
                              hipStream_t stream) {
  const float* x      = (const float*)d_in[0];
  const float* W      = (const float*)d_in[1];
  const float* bias   = (const float*)d_in[2];
  const float* vals   = (const float*)d_in[3];
  const float* sstate = (const float*)d_in[4];
  const int*   rows   = (const int*)d_in[5];
  const int*   cols   = (const int*)d_in[6];
  const int    nc     = in_sizes[3];
  float* out = (float*)d_out;
  float* ws  = (float*)d_ws;

  float* a     = ws;            // 32768 floats
  float* thr   = ws + 32768;    // 4
  float* state = ws + 32772;    // 8192
  float* rec   = ws + 40964;    // 8192
  float* part  = ws + 49156;    // NPB * 8192 (optional)
  const int NPB = 256;
  const bool usePart =
      ws_size >= ((size_t)49156 + (size_t)NPB * PP) * sizeof(float);

  gemm_kernel<<<PP / 4, 256, 0, stream>>>(x, W, bias, a);
  select_kernel<<<1, 1024, 0, stream>>>(a, thr);
  state_init_kernel<<<PP / 256, 256, 0, stream>>>(a, thr, sstate, state, rec);
  if (usePart) {
    spmv_kernel<true><<<NPB, 1024, 0, stream>>>(vals, rows, cols, state, part, nc);
    reduce_partials_kernel<<<PP / 256, 256, 0, stream>>>(part, rec, NPB);
  } else {
    spmv_kernel<false><<<NPB, 1024, 0, stream>>>(vals, rows, cols, state, rec, nc);
  }
  finalize_kernel<<<1, 1024, 0, stream>>>(a, thr, state, rec, out);
}

// Round 2
// 195.873 us; speedup vs baseline: 1.4566x; 1.4566x over previous
//
#include <hip/hip_runtime.h>
#include <math.h>

#define PP 8192
#define DD 4096
#define BBATCH 4
#define NTOT (BBATCH * PP)   // 32768
#define K_LOW 29490          // floor(0.9 * (NTOT-1))

// ---------------- Kernel 1: a = x @ W^T + b  -> [B, P] ----------------
// One wave per output row p; 4 batch accumulators per lane; f64 chunk accum.
// First 64 blocks also zero the 65536-bin histogram (stream-ordered before use).
__global__ __launch_bounds__(256) void gemm_kernel(const float* __restrict__ x,
                                                   const float* __restrict__ W,
                                                   const float* __restrict__ bias,
                                                   float* __restrict__ a,
                                                   unsigned* __restrict__ hist) {
  if (blockIdx.x < 64) {
    const int base = blockIdx.x * 1024 + threadIdx.x;
    #pragma unroll
    for (int j = 0; j < 4; ++j) hist[base + j * 256] = 0u;
  }
  const int wave = threadIdx.x >> 6;
  const int lane = threadIdx.x & 63;
  const int p = (blockIdx.x << 2) + wave;
  const float4* __restrict__ Wrow = (const float4*)(W + (size_t)p * DD);
  const float4* __restrict__ x4 = (const float4*)x;
  double acc0 = 0.0, acc1 = 0.0, acc2 = 0.0, acc3 = 0.0;
  #pragma unroll 4
  for (int i = lane; i < DD / 4; i += 64) {
    float4 w  = Wrow[i];
    float4 v0 = x4[i];
    float4 v1 = x4[1024 + i];
    float4 v2 = x4[2048 + i];
    float4 v3 = x4[3072 + i];
    acc0 += (double)fmaf(w.x, v0.x, fmaf(w.y, v0.y, fmaf(w.z, v0.z, w.w * v0.w)));
    acc1 += (double)fmaf(w.x, v1.x, fmaf(w.y, v1.y, fmaf(w.z, v1.z, w.w * v1.w)));
    acc2 += (double)fmaf(w.x, v2.x, fmaf(w.y, v2.y, fmaf(w.z, v2.z, w.w * v2.w)));
    acc3 += (double)fmaf(w.x, v3.x, fmaf(w.y, v3.y, fmaf(w.z, v3.z, w.w * v3.w)));
  }
  #pragma unroll
  for (int off = 32; off > 0; off >>= 1) {
    acc0 += __shfl_down(acc0, off);
    acc1 += __shfl_down(acc1, off);
    acc2 += __shfl_down(acc2, off);
    acc3 += __shfl_down(acc3, off);
  }
  if (lane == 0) {
    float bp = bias[p];
    a[0 * PP + p] = (float)acc0 + bp;
    a[1 * PP + p] = (float)acc1 + bp;
    a[2 * PP + p] = (float)acc2 + bp;
    a[3 * PP + p] = (float)acc3 + bp;
  }
}

// ---------------- Kernel 2: 65536-bin histogram of top-16 bits of |a| ----------------
__global__ __launch_bounds__(1024) void hist_kernel(const float* __restrict__ a,
                                                    unsigned* __restrict__ hist) {
  const int i = blockIdx.x * 1024 + threadIdx.x;
  unsigned u = __float_as_uint(fabsf(a[i]));
  atomicAdd(&hist[u >> 16], 1u);
}

// ---------------- Kernel 3: locate quantile bucket, exact select, state init ----------------
__global__ __launch_bounds__(1024) void thr_state_kernel(const float* __restrict__ a,
                                                         const unsigned* __restrict__ hist,
                                                         const float* __restrict__ sstate,
                                                         float* __restrict__ thr,
                                                         float* __restrict__ state,
                                                         float* __restrict__ rec) {
  __shared__ unsigned scan[1024];
  __shared__ unsigned list[4096];
  __shared__ unsigned s_nlist;
  __shared__ unsigned s_bucket, s_rank;
  __shared__ unsigned s_vlo;
  __shared__ unsigned wc[16], wm[16];
  __shared__ float s_thr;
  const int tid = threadIdx.x;
  // per-thread partial over 64 bins
  const unsigned base = (unsigned)tid * 64u;
  unsigned part = 0;
  #pragma unroll 8
  for (int j = 0; j < 64; ++j) part += hist[base + j];
  scan[tid] = part;
  if (tid == 0) s_nlist = 0;
  __syncthreads();
  // inclusive Hillis-Steele scan over 1024 partials
  for (int off = 1; off < 1024; off <<= 1) {
    unsigned v = (tid >= off) ? scan[tid - off] : 0u;
    __syncthreads();
    scan[tid] += v;
    __syncthreads();
  }
  const unsigned incl = scan[tid];
  const unsigned excl = incl - part;
  // exactly one thread's segment contains rank K_LOW
  if (excl <= (unsigned)K_LOW && (unsigned)K_LOW < incl) {
    unsigned r = (unsigned)K_LOW - excl;
    unsigned cum = 0;
    for (int j = 0; j < 64; ++j) {
      unsigned c = hist[base + j];
      if (cum + c > r) { s_bucket = base + j; s_rank = r - cum; break; }
      cum += c;
    }
  }
  __syncthreads();
  const unsigned bkt = s_bucket;
  const unsigned r = s_rank;
  // gather candidates with top16 == bkt
  for (int i = tid; i < NTOT; i += 1024) {
    unsigned u = __float_as_uint(fabsf(a[i]));
    if ((u >> 16) == bkt) {
      unsigned idx = atomicAdd(&s_nlist, 1u);
      if (idx < 4096u) list[idx] = u;
    }
  }
  __syncthreads();
  const unsigned m = min(s_nlist, 4096u);
  // brute-force rank-r select within the candidate list
  for (unsigned i = tid; i < m; i += 1024) {
    unsigned ui = list[i];
    unsigned ltc = 0, eqb = 0;
    for (unsigned j = 0; j < m; ++j) {
      unsigned uj = list[j];
      ltc += (uj < ui) ? 1u : 0u;
      eqb += ((uj == ui) && (j < i)) ? 1u : 0u;
    }
    if (ltc + eqb == r) s_vlo = ui;
  }
  __syncthreads();
  const unsigned vlo = s_vlo;
  // one pass: count(u <= vlo) and min(u > vlo)
  unsigned cle = 0, mina = 0xFFFFFFFFu;
  for (int i = tid; i < NTOT; i += 1024) {
    unsigned u = __float_as_uint(fabsf(a[i]));
    cle += (u <= vlo) ? 1u : 0u;
    if (u > vlo) mina = min(mina, u);
  }
  #pragma unroll
  for (int off = 32; off > 0; off >>= 1) {
    cle += __shfl_down(cle, off);
    unsigned o = __shfl_down(mina, off);
    mina = min(mina, o);
  }
  const int lane = tid & 63, wid = tid >> 6;
  if (lane == 0) { wc[wid] = cle; wm[wid] = mina; }
  __syncthreads();
  if (tid == 0) {
    unsigned C = 0, M = 0xFFFFFFFFu;
    for (int w = 0; w < 16; ++w) { C += wc[w]; M = min(M, wm[w]); }
    unsigned vhi = (C > (unsigned)(K_LOW + 1)) ? vlo : M;
    double dlo = (double)__uint_as_float(vlo);
    double dhi = (double)__uint_as_float(vhi);
    double idx = 0.9 * (double)(NTOT - 1);
    double g = idx - floor(idx);
    float t = (float)(dlo + g * (dhi - dlo));
    thr[0] = t;
    s_thr = t;
  }
  __syncthreads();
  const float t = s_thr;
  // fused state init + rec zero
  for (int p = tid; p < PP; p += 1024) {
    float a0 = a[p];
    state[p] = (fabsf(a0) > t) ? a0 : 0.9f * sstate[p];
    rec[p] = 0.0f;
  }
}

// ---------------- Kernel 4: COO SpMV with LDS accumulation ----------------
template <bool USE_PART>
__global__ __launch_bounds__(1024) void spmv_kernel(const float* __restrict__ vals,
                                                    const int* __restrict__ rows,
                                                    const int* __restrict__ cols,
                                                    const float* __restrict__ state,
                                                    float* __restrict__ dst,
                                                    int nc) {
  __shared__ float s_state[PP];
  __shared__ float s_rec[PP];
  for (int i = threadIdx.x; i < PP; i += 1024) {
    s_state[i] = state[i];
    s_rec[i] = 0.0f;
  }
  __syncthreads();
  const int stride = gridDim.x * 1024;
  for (int i = blockIdx.x * 1024 + threadIdx.x; i < nc; i += stride) {
    float v = vals[i];
    int r = rows[i];
    int c = cols[i];
    atomicAdd(&s_rec[r], v * s_state[c]);
  }
  __syncthreads();
  if (USE_PART) {
    float* part = dst + (size_t)blockIdx.x * PP;
    for (int i = threadIdx.x; i < PP; i += 1024) part[i] = s_rec[i];
  } else {
    for (int i = threadIdx.x; i < PP; i += 1024) atomicAdd(&dst[i], s_rec[i]);
  }
}

// ---------------- Kernel 4b: reduce partials -> rec ----------------
__global__ void reduce_partials_kernel(const float* __restrict__ part,
                                       float* __restrict__ rec, int nb) {
  int p = blockIdx.x * blockDim.x + threadIdx.x;
  if (p < PP) {
    float s = 0.0f;
    for (int b = 0; b < nb; ++b) s += part[(size_t)b * PP + p];
    rec[p] = s;
  }
}

// ---------------- Kernel 5: GELU + scalars ----------------
__global__ __launch_bounds__(1024) void finalize_kernel(const float* __restrict__ a,
                                                        const float* __restrict__ thr,
                                                        const float* __restrict__ state,
                                                        const float* __restrict__ rec,
                                                        float* __restrict__ out) {
  __shared__ float wsum[16];
  __shared__ unsigned wcnt[16];
  const float t = thr[0];
  float lsum = 0.0f;
  unsigned lcnt = 0;
  for (int p = threadIdx.x; p < PP; p += 1024) {
    float v = state[p] + 0.1f * rec[p];
    float ns = 0.5f * v * (1.0f + erff(v * 0.70710678118654752440f));
    out[p] = ns;
    if (fabsf(a[p]) > t) { lsum += ns; lcnt++; }
  }
  #pragma unroll
  for (int off = 32; off > 0; off >>= 1) {
    lsum += __shfl_down(lsum, off);
    lcnt += __shfl_down(lcnt, off);
  }
  const int lane = threadIdx.x & 63;
  const int wid = threadIdx.x >> 6;
  if (lane == 0) { wsum[wid] = lsum; wcnt[wid] = lcnt; }
  __syncthreads();
  if (threadIdx.x == 0) {
    float s = 0.0f;
    unsigned c = 0;
    for (int w = 0; w < 16; ++w) { s += wsum[w]; c += wcnt[w]; }
    out[PP] = (float)c;
    out[PP + 1] = (c > 0) ? (s / (float)c) : 0.0f;
  }
}

extern "C" void kernel_launch(void* const* d_in, const int* in_sizes, int n_in,
                              void* d_out, int out_size, void* d_ws, size_t ws_size,
                              hipStream_t stream) {
  const float* x      = (const float*)d_in[0];
  const float* W      = (const float*)d_in[1];
  const float* bias   = (const float*)d_in[2];
  const float* vals   = (const float*)d_in[3];
  const float* sstate = (const float*)d_in[4];
  const int*   rows   = (const int*)d_in[5];
  const int*   cols   = (const int*)d_in[6];
  const int    nc     = in_sizes[3];
  float* out = (float*)d_out;
  float* ws  = (float*)d_ws;

  float*    a     = ws;                       // 32768 floats
  float*    thr   = ws + 32768;               // 4
  float*    state = ws + 32772;               // 8192
  float*    rec   = ws + 40964;               // 8192
  unsigned* hist  = (unsigned*)(ws + 49156);  // 65536 uints
  float*    part  = ws + 49156 + 65536;       // NPB * 8192 (optional)
  const int NPB = 256;
  const bool usePart =
      ws_size >= ((size_t)(49156 + 65536) + (size_t)NPB * PP) * sizeof(float);

  gemm_kernel<<<PP / 4, 256, 0, stream>>>(x, W, bias, a, hist);
  hist_kernel<<<NTOT / 1024, 1024, 0, stream>>>(a, hist);
  thr_state_kernel<<<1, 1024, 0, stream>>>(a, hist, sstate, thr, state, rec);
  if (usePart) {
    spmv_kernel<true><<<NPB, 1024, 0, stream>>>(vals, rows, cols, state, part, nc);
    reduce_partials_kernel<<<PP / 256, 256, 0, stream>>>(part, rec, NPB);
  } else {
    spmv_kernel<false><<<NPB, 1024, 0, stream>>>(vals, rows, cols, state, rec, nc);
  }
  finalize_kernel<<<1, 1024, 0, stream>>>(a, thr, state, rec, out);
}

// Round 3
// 191.934 us; speedup vs baseline: 1.4865x; 1.0205x over previous
//
#include <hip/hip_runtime.h>
#include <math.h>

#define PP 8192
#define DD 4096
#define BBATCH 4
#define NTOT (BBATCH * PP)   // 32768
#define K_LOW 29490          // floor(0.9 * (NTOT-1))
#define NBINS 8192           // bucket = bits(|a|) >> 18, covers all finite floats
#define SCALE 1048576.0f     // 2^20 fixed-point for spmv accumulation
#define INV_SCALE (1.0f / 1048576.0f)
#define LIST_CAP 3072

// ---------------- Kernel 1: a = x @ W^T + b, fused |a| histogram ----------------
// 512 blocks x 1024 threads; x staged in LDS once per block; wave w owns row
// p = blockIdx*16 + w; 4 batch accumulators per lane; f64 chunk accumulation.
__global__ __launch_bounds__(1024) void gemm_hist_kernel(const float* __restrict__ x,
                                                         const float* __restrict__ W,
                                                         const float* __restrict__ bias,
                                                         float* __restrict__ a,
                                                         unsigned* __restrict__ hist) {
  __shared__ float4 s_x[DD];  // 4096 float4 = 64 KB (all 4 batch rows)
  const int tid = threadIdx.x;
  const float4* __restrict__ x4 = (const float4*)x;
  #pragma unroll
  for (int k = 0; k < 4; ++k) s_x[tid + k * 1024] = x4[tid + k * 1024];
  __syncthreads();

  const int wave = tid >> 6;
  const int lane = tid & 63;
  const int p = (blockIdx.x << 4) + wave;
  const float4* __restrict__ Wrow = (const float4*)(W + (size_t)p * DD);
  double acc0 = 0.0, acc1 = 0.0, acc2 = 0.0, acc3 = 0.0;
  #pragma unroll 4
  for (int i = lane; i < DD / 4; i += 64) {
    float4 w  = Wrow[i];
    float4 v0 = s_x[i];
    float4 v1 = s_x[1024 + i];
    float4 v2 = s_x[2048 + i];
    float4 v3 = s_x[3072 + i];
    acc0 += (double)fmaf(w.x, v0.x, fmaf(w.y, v0.y, fmaf(w.z, v0.z, w.w * v0.w)));
    acc1 += (double)fmaf(w.x, v1.x, fmaf(w.y, v1.y, fmaf(w.z, v1.z, w.w * v1.w)));
    acc2 += (double)fmaf(w.x, v2.x, fmaf(w.y, v2.y, fmaf(w.z, v2.z, w.w * v2.w)));
    acc3 += (double)fmaf(w.x, v3.x, fmaf(w.y, v3.y, fmaf(w.z, v3.z, w.w * v3.w)));
  }
  #pragma unroll
  for (int off = 32; off > 0; off >>= 1) {
    acc0 += __shfl_down(acc0, off);
    acc1 += __shfl_down(acc1, off);
    acc2 += __shfl_down(acc2, off);
    acc3 += __shfl_down(acc3, off);
  }
  if (lane == 0) {
    float bp = bias[p];
    float r0 = (float)acc0 + bp;
    float r1 = (float)acc1 + bp;
    float r2 = (float)acc2 + bp;
    float r3 = (float)acc3 + bp;
    a[0 * PP + p] = r0;
    a[1 * PP + p] = r1;
    a[2 * PP + p] = r2;
    a[3 * PP + p] = r3;
    atomicAdd(&hist[__float_as_uint(fabsf(r0)) >> 18], 1u);
    atomicAdd(&hist[__float_as_uint(fabsf(r1)) >> 18], 1u);
    atomicAdd(&hist[__float_as_uint(fabsf(r2)) >> 18], 1u);
    atomicAdd(&hist[__float_as_uint(fabsf(r3)) >> 18], 1u);
  }
}

// ---------------- Kernel 2: exact 0.9-quantile threshold ----------------
// Scan 8192-bin histogram, locate buckets of ranks K_LOW / K_LOW+1, gather
// those buckets' candidates in ONE pass over a, exact in-bucket select.
__global__ __launch_bounds__(1024) void thr_kernel(const float* __restrict__ a,
                                                   const unsigned* __restrict__ hist,
                                                   float* __restrict__ thr) {
  __shared__ unsigned scan[1024];
  __shared__ unsigned list1[LIST_CAP];
  __shared__ unsigned list2[LIST_CAP];
  __shared__ unsigned s_n1, s_n2;
  __shared__ unsigned s_b1, s_r1, s_b2, s_r2;
  __shared__ unsigned s_vlo, s_vhi;
  const int tid = threadIdx.x;
  // per-thread partial over 8 contiguous bins (coalesced uint4 x2)
  const uint4* h4 = (const uint4*)hist;
  uint4 q0 = h4[tid * 2];
  uint4 q1 = h4[tid * 2 + 1];
  unsigned part = q0.x + q0.y + q0.z + q0.w + q1.x + q1.y + q1.z + q1.w;
  scan[tid] = part;
  if (tid == 0) { s_n1 = 0; s_n2 = 0; }
  __syncthreads();
  for (int off = 1; off < 1024; off <<= 1) {
    unsigned v = (tid >= off) ? scan[tid - off] : 0u;
    __syncthreads();
    scan[tid] += v;
    __syncthreads();
  }
  const unsigned incl = scan[tid];
  const unsigned excl = incl - part;
  unsigned bins[8] = {q0.x, q0.y, q0.z, q0.w, q1.x, q1.y, q1.z, q1.w};
  // locate rank K_LOW
  if (excl <= (unsigned)K_LOW && (unsigned)K_LOW < incl) {
    unsigned r = (unsigned)K_LOW - excl, cum = 0;
    #pragma unroll
    for (int j = 0; j < 8; ++j) {
      if (cum + bins[j] > r) { s_b1 = tid * 8 + j; s_r1 = r - cum; break; }
      cum += bins[j];
    }
  }
  // locate rank K_LOW+1
  if (excl <= (unsigned)(K_LOW + 1) && (unsigned)(K_LOW + 1) < incl) {
    unsigned r = (unsigned)(K_LOW + 1) - excl, cum = 0;
    #pragma unroll
    for (int j = 0; j < 8; ++j) {
      if (cum + bins[j] > r) { s_b2 = tid * 8 + j; s_r2 = r - cum; break; }
      cum += bins[j];
    }
  }
  __syncthreads();
  const unsigned b1 = s_b1, r1 = s_r1, b2 = s_b2, r2 = s_r2;
  // gather candidates (one pass)
  for (int i = tid; i < NTOT; i += 1024) {
    unsigned u = __float_as_uint(fabsf(a[i]));
    unsigned bk = u >> 18;
    if (bk == b1) {
      unsigned idx = atomicAdd(&s_n1, 1u);
      if (idx < LIST_CAP) list1[idx] = u;
    } else if (bk == b2) {
      unsigned idx = atomicAdd(&s_n2, 1u);
      if (idx < LIST_CAP) list2[idx] = u;
    }
  }
  __syncthreads();
  const unsigned m1 = min(s_n1, (unsigned)LIST_CAP);
  const unsigned m2 = min(s_n2, (unsigned)LIST_CAP);
  // exact rank-r1 in list1
  for (unsigned i = tid; i < m1; i += 1024) {
    unsigned ui = list1[i];
    unsigned ltc = 0, eqb = 0;
    for (unsigned j = 0; j < m1; ++j) {
      unsigned uj = list1[j];
      ltc += (uj < ui) ? 1u : 0u;
      eqb += ((uj == ui) && (j < i)) ? 1u : 0u;
    }
    unsigned rk = ltc + eqb;
    if (rk == r1) s_vlo = ui;
    if (b2 == b1 && rk == r2) s_vhi = ui;
  }
  // rank-r2 in list2 when different bucket
  if (b2 != b1) {
    for (unsigned i = tid; i < m2; i += 1024) {
      unsigned ui = list2[i];
      unsigned ltc = 0, eqb = 0;
      for (unsigned j = 0; j < m2; ++j) {
        unsigned uj = list2[j];
        ltc += (uj < ui) ? 1u : 0u;
        eqb += ((uj == ui) && (j < i)) ? 1u : 0u;
      }
      if (ltc + eqb == r2) s_vhi = ui;
    }
  }
  __syncthreads();
  if (tid == 0) {
    double dlo = (double)__uint_as_float(s_vlo);
    double dhi = (double)__uint_as_float(s_vhi);
    double idx = 0.9 * (double)(NTOT - 1);
    double g = idx - floor(idx);
    thr[0] = (float)(dlo + g * (dhi - dlo));
  }
}

// ---------------- Kernel 3: COO SpMV, int32 fixed-point LDS accumulation ----------------
// state recomputed inline from (a row0, thr, sstate); ds_add_u32 is native
// (no fp-atomic CAS loop) and exactly commutative -> deterministic.
__global__ __launch_bounds__(1024) void spmv_kernel(const float* __restrict__ vals,
                                                    const int* __restrict__ rows,
                                                    const int* __restrict__ cols,
                                                    const float* __restrict__ a,
                                                    const float* __restrict__ thr,
                                                    const float* __restrict__ sstate,
                                                    int* __restrict__ part,
                                                    int nc) {
  __shared__ float s_state[PP];
  __shared__ int s_rec[PP];
  const int tid = threadIdx.x;
  const float t = thr[0];
  for (int i = tid; i < PP; i += 1024) {
    float a0 = a[i];
    s_state[i] = (fabsf(a0) > t) ? a0 : 0.9f * sstate[i];
    s_rec[i] = 0;
  }
  __syncthreads();
  const int n4 = nc >> 2;
  const int stride = gridDim.x * 1024;
  const float4* __restrict__ v4 = (const float4*)vals;
  const int4* __restrict__ r4 = (const int4*)rows;
  const int4* __restrict__ c4 = (const int4*)cols;
  for (int i = blockIdx.x * 1024 + tid; i < n4; i += stride) {
    float4 v = v4[i];
    int4 r = r4[i];
    int4 c = c4[i];
    atomicAdd((unsigned*)&s_rec[r.x], (unsigned)__float2int_rn(v.x * s_state[c.x] * SCALE));
    atomicAdd((unsigned*)&s_rec[r.y], (unsigned)__float2int_rn(v.y * s_state[c.y] * SCALE));
    atomicAdd((unsigned*)&s_rec[r.z], (unsigned)__float2int_rn(v.z * s_state[c.z] * SCALE));
    atomicAdd((unsigned*)&s_rec[r.w], (unsigned)__float2int_rn(v.w * s_state[c.w] * SCALE));
  }
  // tail (nc % 4 elements) handled by block 0
  if (blockIdx.x == 0 && tid < (nc - (n4 << 2))) {
    int i = (n4 << 2) + tid;
    atomicAdd((unsigned*)&s_rec[rows[i]],
              (unsigned)__float2int_rn(vals[i] * s_state[cols[i]] * SCALE));
  }
  __syncthreads();
  int* dst = part + (size_t)blockIdx.x * PP;
  for (int i = tid; i < PP; i += 1024) dst[i] = s_rec[i];
}

// ---------------- Kernel 4: reduce int partials + GELU -> out ----------------
__global__ __launch_bounds__(256) void reduce_gelu_kernel(const int* __restrict__ part,
                                                          const float* __restrict__ a,
                                                          const float* __restrict__ thr,
                                                          const float* __restrict__ sstate,
                                                          float* __restrict__ out, int nb) {
  const int p = blockIdx.x * 256 + threadIdx.x;
  int s = 0;
  for (int b = 0; b < nb; ++b) s += part[(size_t)b * PP + p];
  float rec = (float)s * INV_SCALE;
  float a0 = a[p];
  float t = thr[0];
  float st = (fabsf(a0) > t) ? a0 : 0.9f * sstate[p];
  float v = st + 0.1f * rec;
  out[p] = 0.5f * v * (1.0f + erff(v * 0.70710678118654752440f));
}

// ---------------- Kernel 5: scalars ----------------
__global__ __launch_bounds__(1024) void scalars_kernel(const float* __restrict__ a,
                                                       const float* __restrict__ thr,
                                                       const float* __restrict__ out_state,
                                                       float* __restrict__ out) {
  __shared__ float wsum[16];
  __shared__ unsigned wcnt[16];
  const float t = thr[0];
  float lsum = 0.0f;
  unsigned lcnt = 0;
  for (int p = threadIdx.x; p < PP; p += 1024) {
    if (fabsf(a[p]) > t) { lsum += out_state[p]; lcnt++; }
  }
  #pragma unroll
  for (int off = 32; off > 0; off >>= 1) {
    lsum += __shfl_down(lsum, off);
    lcnt += __shfl_down(lcnt, off);
  }
  const int lane = threadIdx.x & 63;
  const int wid = threadIdx.x >> 6;
  if (lane == 0) { wsum[wid] = lsum; wcnt[wid] = lcnt; }
  __syncthreads();
  if (threadIdx.x == 0) {
    float s = 0.0f;
    unsigned c = 0;
    for (int w = 0; w < 16; ++w) { s += wsum[w]; c += wcnt[w]; }
    out[PP] = (float)c;
    out[PP + 1] = (c > 0) ? (s / (float)c) : 0.0f;
  }
}

extern "C" void kernel_launch(void* const* d_in, const int* in_sizes, int n_in,
                              void* d_out, int out_size, void* d_ws, size_t ws_size,
                              hipStream_t stream) {
  const float* x      = (const float*)d_in[0];
  const float* W      = (const float*)d_in[1];
  const float* bias   = (const float*)d_in[2];
  const float* vals   = (const float*)d_in[3];
  const float* sstate = (const float*)d_in[4];
  const int*   rows   = (const int*)d_in[5];
  const int*   cols   = (const int*)d_in[6];
  const int    nc     = in_sizes[3];
  float* out = (float*)d_out;
  float* ws  = (float*)d_ws;

  const int NPB = 256;
  float*    a    = ws;                        // 32768 floats
  float*    thr  = ws + 32768;                // 16
  unsigned* hist = (unsigned*)(ws + 32784);   // 8192 bins
  int*      part = (int*)(ws + 32784 + NBINS);// NPB * 8192 ints

  hipMemsetAsync(hist, 0, NBINS * sizeof(unsigned), stream);
  gemm_hist_kernel<<<PP / 16, 1024, 0, stream>>>(x, W, bias, a, hist);
  thr_kernel<<<1, 1024, 0, stream>>>(a, hist, thr);
  spmv_kernel<<<NPB, 1024, 0, stream>>>(vals, rows, cols, a, thr, sstate, part, nc);
  reduce_gelu_kernel<<<PP / 256, 256, 0, stream>>>(part, a, thr, sstate, out, NPB);
  scalars_kernel<<<1, 1024, 0, stream>>>(a, thr, out, out);
}

// Round 4
// 82.186 us; speedup vs baseline: 3.4716x; 2.3354x over previous
//
#include <hip/hip_runtime.h>
#include <math.h>

#define PP 8192
#define DD 4096
#define BBATCH 4
#define NTOT (BBATCH * PP)   // 32768
#define K_LOW 29490          // floor(0.9 * (NTOT-1))
#define NBINS 8192           // bucket = bits(|a|) >> 18
#define SCALE 1048576.0f     // 2^20 fixed-point for spmv accumulation
#define INV_SCALE (1.0f / 1048576.0f)
#define LIST_CAP 3072

__device__ __forceinline__ float dot4(float4 w, float4 v) {
  return fmaf(w.x, v.x, fmaf(w.y, v.y, fmaf(w.z, v.z, w.w * v.w)));
}

// ---------------- Kernel 1: a = x @ W^T + b ----------------
// 1024 blocks x 256 thr; wave w handles rows p0=blk*8+2w, p0+1 (shared x loads).
// No LDS, no atomics; x from L1/L2. First 64 blocks zero hist/rec (used later).
__global__ __launch_bounds__(256, 4) void gemm_kernel(const float* __restrict__ x,
                                                      const float* __restrict__ W,
                                                      const float* __restrict__ bias,
                                                      float* __restrict__ a,
                                                      unsigned* __restrict__ hist,
                                                      int* __restrict__ rec) {
  if (blockIdx.x < 32) {
    hist[blockIdx.x * 256 + threadIdx.x] = 0u;
  } else if (blockIdx.x < 64) {
    rec[(blockIdx.x - 32) * 256 + threadIdx.x] = 0;
  }
  const int wave = threadIdx.x >> 6;
  const int lane = threadIdx.x & 63;
  const int p0 = blockIdx.x * 8 + wave * 2;
  const float4* __restrict__ W0 = (const float4*)(W + (size_t)p0 * DD);
  const float4* __restrict__ W1 = W0 + (DD / 4);
  const float4* __restrict__ x4 = (const float4*)x;
  double a00 = 0.0, a01 = 0.0, a02 = 0.0, a03 = 0.0;
  double a10 = 0.0, a11 = 0.0, a12 = 0.0, a13 = 0.0;
  #pragma unroll 4
  for (int k = 0; k < 16; ++k) {
    const int i = lane + k * 64;
    float4 w0 = W0[i];
    float4 w1 = W1[i];
    float4 v0 = x4[i];
    float4 v1 = x4[1024 + i];
    float4 v2 = x4[2048 + i];
    float4 v3 = x4[3072 + i];
    a00 += (double)dot4(w0, v0);
    a01 += (double)dot4(w0, v1);
    a02 += (double)dot4(w0, v2);
    a03 += (double)dot4(w0, v3);
    a10 += (double)dot4(w1, v0);
    a11 += (double)dot4(w1, v1);
    a12 += (double)dot4(w1, v2);
    a13 += (double)dot4(w1, v3);
  }
  #pragma unroll
  for (int off = 32; off > 0; off >>= 1) {
    a00 += __shfl_down(a00, off);
    a01 += __shfl_down(a01, off);
    a02 += __shfl_down(a02, off);
    a03 += __shfl_down(a03, off);
    a10 += __shfl_down(a10, off);
    a11 += __shfl_down(a11, off);
    a12 += __shfl_down(a12, off);
    a13 += __shfl_down(a13, off);
  }
  if (lane == 0) {
    float b0 = bias[p0];
    float b1 = bias[p0 + 1];
    a[0 * PP + p0] = (float)a00 + b0;
    a[1 * PP + p0] = (float)a01 + b0;
    a[2 * PP + p0] = (float)a02 + b0;
    a[3 * PP + p0] = (float)a03 + b0;
    a[0 * PP + p0 + 1] = (float)a10 + b1;
    a[1 * PP + p0 + 1] = (float)a11 + b1;
    a[2 * PP + p0 + 1] = (float)a12 + b1;
    a[3 * PP + p0 + 1] = (float)a13 + b1;
  }
}

// ---------------- Kernel 2: histogram via per-block LDS (native ds_add_u32) ----------------
// 8 blocks x 1024 thr x 4 elems; hot-bin contention /8 per block; global merge
// via spread atomics (<=8 per address).
__global__ __launch_bounds__(1024) void hist_kernel(const float* __restrict__ a,
                                                    unsigned* __restrict__ hist) {
  __shared__ unsigned h[NBINS];
  const int tid = threadIdx.x;
  #pragma unroll
  for (int j = 0; j < NBINS / 1024; ++j) h[tid + j * 1024] = 0u;
  __syncthreads();
  const int base = blockIdx.x * 4096 + tid;
  #pragma unroll
  for (int k = 0; k < 4; ++k) {
    unsigned u = __float_as_uint(fabsf(a[base + k * 1024]));
    atomicAdd(&h[u >> 18], 1u);
  }
  __syncthreads();
  #pragma unroll
  for (int j = 0; j < NBINS / 1024; ++j) {
    unsigned c = h[tid + j * 1024];
    if (c) atomicAdd(&hist[tid + j * 1024], c);
  }
}

// ---------------- Kernel 3: exact 0.9-quantile threshold ----------------
__global__ __launch_bounds__(1024) void thr_kernel(const float* __restrict__ a,
                                                   const unsigned* __restrict__ hist,
                                                   float* __restrict__ thr) {
  __shared__ unsigned scan[1024];
  __shared__ unsigned list1[LIST_CAP];
  __shared__ unsigned list2[LIST_CAP];
  __shared__ unsigned s_n1, s_n2;
  __shared__ unsigned s_b1, s_r1, s_b2, s_r2;
  __shared__ unsigned s_vlo, s_vhi;
  const int tid = threadIdx.x;
  const uint4* h4 = (const uint4*)hist;
  uint4 q0 = h4[tid * 2];
  uint4 q1 = h4[tid * 2 + 1];
  unsigned part = q0.x + q0.y + q0.z + q0.w + q1.x + q1.y + q1.z + q1.w;
  scan[tid] = part;
  if (tid == 0) { s_n1 = 0; s_n2 = 0; }
  __syncthreads();
  for (int off = 1; off < 1024; off <<= 1) {
    unsigned v = (tid >= off) ? scan[tid - off] : 0u;
    __syncthreads();
    scan[tid] += v;
    __syncthreads();
  }
  const unsigned incl = scan[tid];
  const unsigned excl = incl - part;
  unsigned bins[8] = {q0.x, q0.y, q0.z, q0.w, q1.x, q1.y, q1.z, q1.w};
  if (excl <= (unsigned)K_LOW && (unsigned)K_LOW < incl) {
    unsigned r = (unsigned)K_LOW - excl, cum = 0;
    #pragma unroll
    for (int j = 0; j < 8; ++j) {
      if (cum + bins[j] > r) { s_b1 = tid * 8 + j; s_r1 = r - cum; break; }
      cum += bins[j];
    }
  }
  if (excl <= (unsigned)(K_LOW + 1) && (unsigned)(K_LOW + 1) < incl) {
    unsigned r = (unsigned)(K_LOW + 1) - excl, cum = 0;
    #pragma unroll
    for (int j = 0; j < 8; ++j) {
      if (cum + bins[j] > r) { s_b2 = tid * 8 + j; s_r2 = r - cum; break; }
      cum += bins[j];
    }
  }
  __syncthreads();
  const unsigned b1 = s_b1, r1 = s_r1, b2 = s_b2, r2 = s_r2;
  for (int i = tid; i < NTOT; i += 1024) {
    unsigned u = __float_as_uint(fabsf(a[i]));
    unsigned bk = u >> 18;
    if (bk == b1) {
      unsigned idx = atomicAdd(&s_n1, 1u);
      if (idx < LIST_CAP) list1[idx] = u;
    } else if (bk == b2) {
      unsigned idx = atomicAdd(&s_n2, 1u);
      if (idx < LIST_CAP) list2[idx] = u;
    }
  }
  __syncthreads();
  const unsigned m1 = min(s_n1, (unsigned)LIST_CAP);
  const unsigned m2 = min(s_n2, (unsigned)LIST_CAP);
  for (unsigned i = tid; i < m1; i += 1024) {
    unsigned ui = list1[i];
    unsigned ltc = 0, eqb = 0;
    for (unsigned j = 0; j < m1; ++j) {
      unsigned uj = list1[j];
      ltc += (uj < ui) ? 1u : 0u;
      eqb += ((uj == ui) && (j < i)) ? 1u : 0u;
    }
    unsigned rk = ltc + eqb;
    if (rk == r1) s_vlo = ui;
    if (b2 == b1 && rk == r2) s_vhi = ui;
  }
  if (b2 != b1) {
    for (unsigned i = tid; i < m2; i += 1024) {
      unsigned ui = list2[i];
      unsigned ltc = 0, eqb = 0;
      for (unsigned j = 0; j < m2; ++j) {
        unsigned uj = list2[j];
        ltc += (uj < ui) ? 1u : 0u;
        eqb += ((uj == ui) && (j < i)) ? 1u : 0u;
      }
      if (ltc + eqb == r2) s_vhi = ui;
    }
  }
  __syncthreads();
  if (tid == 0) {
    double dlo = (double)__uint_as_float(s_vlo);
    double dhi = (double)__uint_as_float(s_vhi);
    double idx = 0.9 * (double)(NTOT - 1);
    double g = idx - floor(idx);
    thr[0] = (float)(dlo + g * (dhi - dlo));
  }
}

// ---------------- Kernel 4: COO SpMV, int fixed-point LDS accum, direct global merge ----------------
__global__ __launch_bounds__(1024) void spmv_kernel(const float* __restrict__ vals,
                                                    const int* __restrict__ rows,
                                                    const int* __restrict__ cols,
                                                    const float* __restrict__ a,
                                                    const float* __restrict__ thr,
                                                    const float* __restrict__ sstate,
                                                    int* __restrict__ rec,
                                                    int nc) {
  __shared__ float s_state[PP];
  __shared__ int s_rec[PP];
  const int tid = threadIdx.x;
  const float t = thr[0];
  for (int i = tid; i < PP; i += 1024) {
    float a0 = a[i];
    s_state[i] = (fabsf(a0) > t) ? a0 : 0.9f * sstate[i];
    s_rec[i] = 0;
  }
  __syncthreads();
  const int n4 = nc >> 2;
  const int stride = gridDim.x * 1024;
  const float4* __restrict__ v4 = (const float4*)vals;
  const int4* __restrict__ r4 = (const int4*)rows;
  const int4* __restrict__ c4 = (const int4*)cols;
  for (int i = blockIdx.x * 1024 + tid; i < n4; i += stride) {
    float4 v = v4[i];
    int4 r = r4[i];
    int4 c = c4[i];
    atomicAdd((unsigned*)&s_rec[r.x], (unsigned)__float2int_rn(v.x * s_state[c.x] * SCALE));
    atomicAdd((unsigned*)&s_rec[r.y], (unsigned)__float2int_rn(v.y * s_state[c.y] * SCALE));
    atomicAdd((unsigned*)&s_rec[r.z], (unsigned)__float2int_rn(v.z * s_state[c.z] * SCALE));
    atomicAdd((unsigned*)&s_rec[r.w], (unsigned)__float2int_rn(v.w * s_state[c.w] * SCALE));
  }
  if (blockIdx.x == 0 && tid < (nc - (n4 << 2))) {
    int i = (n4 << 2) + tid;
    atomicAdd((unsigned*)&s_rec[rows[i]],
              (unsigned)__float2int_rn(vals[i] * s_state[cols[i]] * SCALE));
  }
  __syncthreads();
  for (int i = tid; i < PP; i += 1024)
    atomicAdd((unsigned*)&rec[i], (unsigned)s_rec[i]);
}

// ---------------- Kernel 5: GELU -> out ----------------
__global__ __launch_bounds__(256) void reduce_gelu_kernel(const int* __restrict__ rec,
                                                          const float* __restrict__ a,
                                                          const float* __restrict__ thr,
                                                          const float* __restrict__ sstate,
                                                          float* __restrict__ out) {
  const int p = blockIdx.x * 256 + threadIdx.x;
  float r = (float)rec[p] * INV_SCALE;
  float a0 = a[p];
  float t = thr[0];
  float st = (fabsf(a0) > t) ? a0 : 0.9f * sstate[p];
  float v = st + 0.1f * r;
  out[p] = 0.5f * v * (1.0f + erff(v * 0.70710678118654752440f));
}

// ---------------- Kernel 6: scalars ----------------
__global__ __launch_bounds__(1024) void scalars_kernel(const float* __restrict__ a,
                                                       const float* __restrict__ thr,
                                                       const float* __restrict__ out_state,
                                                       float* __restrict__ out) {
  __shared__ float wsum[16];
  __shared__ unsigned wcnt[16];
  const float t = thr[0];
  float lsum = 0.0f;
  unsigned lcnt = 0;
  for (int p = threadIdx.x; p < PP; p += 1024) {
    if (fabsf(a[p]) > t) { lsum += out_state[p]; lcnt++; }
  }
  #pragma unroll
  for (int off = 32; off > 0; off >>= 1) {
    lsum += __shfl_down(lsum, off);
    lcnt += __shfl_down(lcnt, off);
  }
  const int lane = threadIdx.x & 63;
  const int wid = threadIdx.x >> 6;
  if (lane == 0) { wsum[wid] = lsum; wcnt[wid] = lcnt; }
  __syncthreads();
  if (threadIdx.x == 0) {
    float s = 0.0f;
    unsigned c = 0;
    for (int w = 0; w < 16; ++w) { s += wsum[w]; c += wcnt[w]; }
    out[PP] = (float)c;
    out[PP + 1] = (c > 0) ? (s / (float)c) : 0.0f;
  }
}

extern "C" void kernel_launch(void* const* d_in, const int* in_sizes, int n_in,
                              void* d_out, int out_size, void* d_ws, size_t ws_size,
                              hipStream_t stream) {
  const float* x      = (const float*)d_in[0];
  const float* W      = (const float*)d_in[1];
  const float* bias   = (const float*)d_in[2];
  const float* vals   = (const float*)d_in[3];
  const float* sstate = (const float*)d_in[4];
  const int*   rows   = (const int*)d_in[5];
  const int*   cols   = (const int*)d_in[6];
  const int    nc     = in_sizes[3];
  float* out = (float*)d_out;
  float* ws  = (float*)d_ws;

  float*    a    = ws;                         // 32768 floats
  float*    thr  = ws + 32768;                 // 16
  unsigned* hist = (unsigned*)(ws + 32784);    // 8192 bins
  int*      rec  = (int*)(ws + 32784 + NBINS); // 8192 ints

  gemm_kernel<<<PP / 8, 256, 0, stream>>>(x, W, bias, a, hist, rec);
  hist_kernel<<<NTOT / 4096, 1024, 0, stream>>>(a, hist);
  thr_kernel<<<1, 1024, 0, stream>>>(a, hist, thr);
  spmv_kernel<<<256, 1024, 0, stream>>>(vals, rows, cols, a, thr, sstate, rec, nc);
  reduce_gelu_kernel<<<PP / 256, 256, 0, stream>>>(rec, a, thr, sstate, out);
  scalars_kernel<<<1, 1024, 0, stream>>>(a, thr, out, out);
}